// Round 1
// 633.527 us; speedup vs baseline: 1.0611x; 1.0611x over previous
//
#include <hip/hip_runtime.h>
#include <math.h>

constexpr int NUM_GRAPHS = 1024;

// ---------------------------------------------------------------------------
// Non-temporal float4 load: x is streamed exactly once, never reused -> tell
// the cache hierarchy not to retain it.
// ---------------------------------------------------------------------------
typedef float f4_t __attribute__((ext_vector_type(4)));
__device__ __forceinline__ float4 nt_load(const float4* p) {
    f4_t v = __builtin_nontemporal_load((const f4_t*)p);
    return make_float4(v.x, v.y, v.z, v.w);
}

// ---------------------------------------------------------------------------
// Kernel 0: detect whether `batch` was staged as int32 or int64.
// int64 (LE, values < 1024): every odd 32-bit word is 0. int32 (sorted graph
// ids, mostly nonzero): odd words in the bulk are nonzero. flag=1 -> int32.
// flag must be zeroed before launch (hipMemsetAsync).
// ---------------------------------------------------------------------------
__global__ void detect_i32_kernel(const int* __restrict__ words, int n,
                                  int* __restrict__ flag) {
    const int stride = gridDim.x * blockDim.x;
    int acc = 0;
    for (int j = 1 + 2 * (int)(blockIdx.x * blockDim.x + threadIdx.x); j < n;
         j += 2 * stride)
        acc |= words[j];
    if (__any(acc != 0)) {
        if ((threadIdx.x & 63) == 0) atomicOr(flag, 1);
    }
}

// ---------------------------------------------------------------------------
// Kernel 1: segment starts from the sorted batch vector.
// seg[g] = first node index with batch >= g; seg[NUM_GRAPHS] = n.
// ---------------------------------------------------------------------------
__global__ void seg_start_kernel(const int* __restrict__ words, int n,
                                 const int* __restrict__ flag,
                                 int* __restrict__ seg) {
    int i = blockIdx.x * blockDim.x + threadIdx.x;
    if (i >= n) return;
    const bool is32 = (*flag != 0);
    int b    = is32 ? words[i] : words[2 * i];
    int prev = (i == 0) ? -1 : (is32 ? words[i - 1] : words[2 * (i - 1)]);
    for (int g = prev + 1; g <= b; ++g) seg[g] = i;
    if (i == n - 1)
        for (int g = b + 1; g <= NUM_GRAPHS; ++g) seg[g] = n;
}

// ---------------------------------------------------------------------------
// Kernel 2: fully fused pooling. ONE block per graph (grid=1024), 4 waves per
// block. The graph's rows are split into 4 CONTIGUOUS chunks, one per wave,
// so each wave streams sequential memory (~120 KB) instead of 1 KB bursts at
// a 16 KB stride (the old 16-way row striping — DRAM-page hostile, measured
// ~1.7 TB/s). Lane l owns columns 4l..4l+3; a wave covers one 1 KB row per
// load group, 4 rows in flight.
// Block reduces across its 4 waves in LDS and writes the FINAL output
// (mean/max/att) directly — no partials buffer, no combine kernel.
// ---------------------------------------------------------------------------
__global__ __launch_bounds__(256) void pool_fused_kernel(
    const float* __restrict__ x, const float* __restrict__ att_w,
    const float* __restrict__ att_b, const int* __restrict__ seg,
    float* __restrict__ out) {
    const int g    = blockIdx.x;
    const int lane = threadIdx.x & 63;
    const int w    = threadIdx.x >> 6;

    const int s0    = seg[g];
    const int e0    = seg[g + 1];
    const int cnt   = e0 - s0;
    const int chunk = (cnt + 3) >> 2;               // rows per wave (contiguous)
    const int wbeg  = min(s0 + w * chunk, e0);
    const int wend  = min(wbeg + chunk, e0);

    const float4* __restrict__ x4 = (const float4*)x;
    const float4 wv   = ((const float4*)att_w)[lane];
    const float  bias = att_b[0];

    float sx = 0.f, sy = 0.f, sz = 0.f, sw = 0.f;
    float mx = -INFINITY, my = -INFINITY, mz = -INFINITY, mw = -INFINITY;
    float ax = 0.f, ay = 0.f, az = 0.f, aw = 0.f;

    auto proc4 = [&](const float4* v) {
        float p[4];
#pragma unroll
        for (int r = 0; r < 4; ++r)
            p[r] = v[r].x * wv.x + v[r].y * wv.y + v[r].z * wv.z + v[r].w * wv.w;
#pragma unroll
        for (int off = 32; off >= 1; off >>= 1) {
#pragma unroll
            for (int r = 0; r < 4; ++r)
                p[r] += __shfl_xor(p[r], off, 64);
        }
#pragma unroll
        for (int r = 0; r < 4; ++r) {
            const float sig = 1.0f / (1.0f + __expf(-(p[r] + bias)));
            sx += v[r].x; sy += v[r].y; sz += v[r].z; sw += v[r].w;
            mx = fmaxf(mx, v[r].x); my = fmaxf(my, v[r].y);
            mz = fmaxf(mz, v[r].z); mw = fmaxf(mw, v[r].w);
            ax += v[r].x * sig; ay += v[r].y * sig;
            az += v[r].z * sig; aw += v[r].w * sig;
        }
    };

    int i = wbeg;
    if (i + 4 <= wend) {                       // software pipeline, depth 4
        float4 v[4];
#pragma unroll
        for (int r = 0; r < 4; ++r)
            v[r] = nt_load(x4 + (size_t)(i + r) * 64 + lane);
        int nb = i + 4;
        while (nb + 4 <= wend) {
            float4 vn[4];
#pragma unroll
            for (int r = 0; r < 4; ++r)
                vn[r] = nt_load(x4 + (size_t)(nb + r) * 64 + lane);
            proc4(v);
#pragma unroll
            for (int r = 0; r < 4; ++r) v[r] = vn[r];
            nb += 4;
        }
        proc4(v);
        i = nb;
    }
    for (; i < wend; ++i) {                    // remainder (<= 3 rows)
        const float4 v = nt_load(x4 + (size_t)i * 64 + lane);
        float p = v.x * wv.x + v.y * wv.y + v.z * wv.z + v.w * wv.w;
#pragma unroll
        for (int off = 32; off >= 1; off >>= 1)
            p += __shfl_xor(p, off, 64);
        const float sig = 1.0f / (1.0f + __expf(-(p + bias)));
        sx += v.x; sy += v.y; sz += v.z; sw += v.w;
        mx = fmaxf(mx, v.x); my = fmaxf(my, v.y);
        mz = fmaxf(mz, v.z); mw = fmaxf(mw, v.w);
        ax += v.x * sig; ay += v.y * sig; az += v.z * sig; aw += v.w * sig;
    }

    // cross-wave reduction in LDS, then final output (one section per wave)
    __shared__ float4 lsum[4][64];
    __shared__ float4 lmax[4][64];
    __shared__ float4 latt[4][64];
    lsum[w][lane] = make_float4(sx, sy, sz, sw);
    lmax[w][lane] = make_float4(mx, my, mz, mw);
    latt[w][lane] = make_float4(ax, ay, az, aw);
    __syncthreads();

    float4* __restrict__ o = (float4*)(out + (size_t)g * 768);
    if (w == 0) {                              // mean pool
        float4 S = lsum[0][lane];
#pragma unroll
        for (int ww = 1; ww < 4; ++ww) {
            float4 b = lsum[ww][lane];
            S.x += b.x; S.y += b.y; S.z += b.z; S.w += b.w;
        }
        const float inv = 1.0f / (float)(cnt > 0 ? cnt : 1);
        S.x *= inv; S.y *= inv; S.z *= inv; S.w *= inv;
        o[lane] = S;
    } else if (w == 1) {                       // max pool
        float4 M = lmax[0][lane];
#pragma unroll
        for (int ww = 1; ww < 4; ++ww) {
            float4 b = lmax[ww][lane];
            M.x = fmaxf(M.x, b.x); M.y = fmaxf(M.y, b.y);
            M.z = fmaxf(M.z, b.z); M.w = fmaxf(M.w, b.w);
        }
        o[64 + lane] = M;
    } else if (w == 2) {                       // attention pool
        float4 A = latt[0][lane];
#pragma unroll
        for (int ww = 1; ww < 4; ++ww) {
            float4 b = latt[ww][lane];
            A.x += b.x; A.y += b.y; A.z += b.z; A.w += b.w;
        }
        o[128 + lane] = A;
    }
}

extern "C" void kernel_launch(void* const* d_in, const int* in_sizes, int n_in,
                              void* d_out, int out_size, void* d_ws, size_t ws_size,
                              hipStream_t stream) {
    const float* x           = (const float*)d_in[0];
    const int*   batch_words = (const int*)d_in[1];
    const float* att_w       = (const float*)d_in[2];
    const float* att_b       = (const float*)d_in[3];
    float*       out         = (float*)d_out;
    const int n = in_sizes[1];

    int* flag = (int*)d_ws;                     // 1 int
    int* seg  = ((int*)d_ws) + 8;               // NUM_GRAPHS+1 ints

    hipMemsetAsync(flag, 0, sizeof(int), stream);
    detect_i32_kernel<<<256, 256, 0, stream>>>(batch_words, n, flag);
    seg_start_kernel<<<(n + 255) / 256, 256, 0, stream>>>(batch_words, n, flag, seg);
    pool_fused_kernel<<<NUM_GRAPHS, 256, 0, stream>>>(x, att_w, att_b, seg, out);
}